// Round 1
// baseline (23320.193 us; speedup 1.0000x reference)
//
#include <hip/hip_runtime.h>
#include <hip/hip_bf16.h>

#define B_SZ   256
#define T_SZ   256
#define FUT    32
#define TF_SZ  (T_SZ + FUT)
#define HIDN   1024
#define INDIM  64
#define OUTDIM 64

typedef __attribute__((ext_vector_type(8))) short bf16x8;
typedef __attribute__((ext_vector_type(4))) float f32x4;

__device__ __forceinline__ float bf2f(unsigned short u) {
    union { unsigned int i; float f; } v; v.i = (unsigned int)u << 16; return v.f;
}
__device__ __forceinline__ unsigned short f2bf(float f) {
    union { float f; unsigned int i; } v; v.f = f;
    unsigned int r = v.i + 0x7FFFu + ((v.i >> 16) & 1u);
    return (unsigned short)(r >> 16);
}
__device__ __forceinline__ float sigm(float x) { return 1.0f / (1.0f + __expf(-x)); }

// ---------------------------------------------------------------------------
// GEMM + fused LSTM cell update.
// gates[b][4H] = a[b][:] @ W^T + b_ih + b_hh, where a = [a1 (K1) | a2 (K2)].
// W is bf16 [4H][K1+K2] row-major (gate-major rows: i, f, g, o blocks of HIDN).
// Each block: 64 batch rows x 16 hidden units x 4 gates. Grid (4, 64).
// Epilogue applies the cell update in-register (c fp32 in place, h -> bf16).
// ---------------------------------------------------------------------------
__global__ __launch_bounds__(256) void lstm_gemm_cell(
    const unsigned short* __restrict__ a1, int K1, int s1,
    const unsigned short* __restrict__ a2, int K2, int s2,
    const unsigned short* __restrict__ W,
    const float* __restrict__ b_ih, const float* __restrict__ b_hh,
    float* __restrict__ cbuf,
    unsigned short* __restrict__ hdst, int hs)
{
    const int K = K1 + K2;
    const int lane = threadIdx.x & 63;
    const int wv   = threadIdx.x >> 6;
    const int am   = lane & 15;   // A-operand M index / B-operand N index
    const int ah   = lane >> 4;   // K sub-block selector
    const int rowbase = blockIdx.x * 64 + wv * 16;
    const int jb      = blockIdx.y * 16;

    f32x4 acc0 = {0.f,0.f,0.f,0.f}, acc1 = {0.f,0.f,0.f,0.f};
    f32x4 acc2 = {0.f,0.f,0.f,0.f}, acc3 = {0.f,0.f,0.f,0.f};

    const int arow = rowbase + am;
    const unsigned short* wrow = W + (size_t)(jb + am) * K;
    const size_t gstr = (size_t)HIDN * K;

    for (int k = 0; k < K; k += 32) {
        const int koff = k + ah * 8;
        const unsigned short* ap = (k < K1)
            ? (a1 + (size_t)arow * s1 + koff)
            : (a2 + (size_t)arow * s2 + (koff - K1));
        bf16x8 av = *(const bf16x8*)ap;
        bf16x8 b0 = *(const bf16x8*)(wrow + koff);
        bf16x8 b1 = *(const bf16x8*)(wrow + gstr + koff);
        bf16x8 b2 = *(const bf16x8*)(wrow + 2 * gstr + koff);
        bf16x8 b3 = *(const bf16x8*)(wrow + 3 * gstr + koff);
        acc0 = __builtin_amdgcn_mfma_f32_16x16x32_bf16(av, b0, acc0, 0, 0, 0);
        acc1 = __builtin_amdgcn_mfma_f32_16x16x32_bf16(av, b1, acc1, 0, 0, 0);
        acc2 = __builtin_amdgcn_mfma_f32_16x16x32_bf16(av, b2, acc2, 0, 0, 0);
        acc3 = __builtin_amdgcn_mfma_f32_16x16x32_bf16(av, b3, acc3, 0, 0, 0);
    }

    const int j = jb + am;
    const float bi = b_ih[j]            + b_hh[j];
    const float bf = b_ih[HIDN + j]     + b_hh[HIDN + j];
    const float bg = b_ih[2 * HIDN + j] + b_hh[2 * HIDN + j];
    const float bo = b_ih[3 * HIDN + j] + b_hh[3 * HIDN + j];
#pragma unroll
    for (int r = 0; r < 4; ++r) {
        const int row = rowbase + ah * 4 + r;   // C/D layout: row=(lane>>4)*4+reg
        const float ig = sigm(acc0[r] + bi);
        const float fg = sigm(acc1[r] + bf);
        const float gg = tanhf(acc2[r] + bg);
        const float og = sigm(acc3[r] + bo);
        const size_t ci = (size_t)row * HIDN + j;
        const float cn = fg * cbuf[ci] + ig * gg;
        cbuf[ci] = cn;
        hdst[(size_t)row * hs + j] = f2bf(og * tanhf(cn));
    }
}

// ---------------------------------------------------------------------------
// out[b][t][:] = h2 @ W_lin^T + b_lin; optionally x_next = out @ W_o2i^T + b_o2i
// Block: 4 rows x 64 cols, grid 64.
// ---------------------------------------------------------------------------
__global__ __launch_bounds__(256) void out_kernel(
    const unsigned short* __restrict__ h2,   // row stride 2048 (h2 region)
    const unsigned short* __restrict__ Wlin, // [64][1024] bf16
    const float* __restrict__ blin,
    float* __restrict__ outp, int t,
    const unsigned short* __restrict__ Wo2i, // [64][64] bf16
    const float* __restrict__ bo2i,
    unsigned short* __restrict__ xfut, int do_fb)
{
    __shared__ unsigned short h2s[4][HIDN];
    __shared__ float outs[4][OUTDIM];
    const int tid = threadIdx.x;
    const int rl  = tid >> 6;
    const int col = tid & 63;
    const int rowbase = blockIdx.x * 4;

    for (int i = tid; i < 4 * HIDN / 8; i += 256) {
        const int rr = i >> 7, kk = (i & 127) * 8;
        *(bf16x8*)&h2s[rr][kk] =
            *(const bf16x8*)&h2[(size_t)(rowbase + rr) * 2048 + kk];
    }
    __syncthreads();

    float acc = blin[col];
    const unsigned short* wrow = Wlin + (size_t)col * HIDN;
    for (int k = 0; k < HIDN; k += 8) {
        bf16x8 hv = *(const bf16x8*)&h2s[rl][k];
        bf16x8 wv = *(const bf16x8*)&wrow[k];
#pragma unroll
        for (int u = 0; u < 8; ++u)
            acc += bf2f((unsigned short)hv[u]) * bf2f((unsigned short)wv[u]);
    }
    const int row = rowbase + rl;
    outp[((size_t)row * TF_SZ + t) * OUTDIM + col] = acc;

    if (do_fb) {
        outs[rl][col] = acc;
        __syncthreads();
        float x = bo2i[col];
        const unsigned short* w2 = Wo2i + (size_t)col * OUTDIM;
#pragma unroll 8
        for (int jj = 0; jj < OUTDIM; ++jj)
            x += outs[rl][jj] * bf2f(w2[jj]);
        xfut[(size_t)row * INDIM + col] = f2bf(x);
    }
}

// fp32 -> bf16 with strided destination (row interleave for [W_ih | W_hh])
__global__ void conv_strided(const float* __restrict__ src,
                             unsigned short* __restrict__ dst,
                             int cols, int dstride, int doff, int total)
{
    const int idx = blockIdx.x * 256 + threadIdx.x;
    if (idx >= total) return;
    const int r = idx / cols, c = idx - r * cols;
    dst[(size_t)r * dstride + doff + c] = f2bf(src[idx]);
}

// input [B][T][F] fp32 -> [T][B][F] bf16
__global__ void conv_x(const float* __restrict__ src,
                       unsigned short* __restrict__ dst)
{
    const int idx = blockIdx.x * 256 + threadIdx.x; // total = 256*256*64
    const int f = idx & 63, t = (idx >> 6) & 255, b = idx >> 14;
    dst[((size_t)t * B_SZ + b) * INDIM + f] = f2bf(src[idx]);
}

extern "C" void kernel_launch(void* const* d_in, const int* in_sizes, int n_in,
                              void* d_out, int out_size, void* d_ws, size_t ws_size,
                              hipStream_t stream)
{
    const float* input = (const float*)d_in[0];
    const float* W_ih1 = (const float*)d_in[1];
    const float* W_hh1 = (const float*)d_in[2];
    const float* b_ih1 = (const float*)d_in[3];
    const float* b_hh1 = (const float*)d_in[4];
    const float* W_ih2 = (const float*)d_in[5];
    const float* W_hh2 = (const float*)d_in[6];
    const float* b_ih2 = (const float*)d_in[7];
    const float* b_hh2 = (const float*)d_in[8];
    const float* W_lin = (const float*)d_in[9];
    const float* b_lin = (const float*)d_in[10];
    const float* W_o2i = (const float*)d_in[11];
    const float* b_o2i = (const float*)d_in[12];
    float* outp = (float*)d_out;

    char* ws = (char*)d_ws;
    unsigned short* Wcat1 = (unsigned short*)ws; ws += (size_t)4096 * 1088 * 2;
    unsigned short* Wcat2 = (unsigned short*)ws; ws += (size_t)4096 * 2048 * 2;
    unsigned short* Wlinb = (unsigned short*)ws; ws += (size_t)64 * 1024 * 2;
    unsigned short* Wo2ib = (unsigned short*)ws; ws += (size_t)64 * 64 * 2;
    unsigned short* xbf   = (unsigned short*)ws; ws += (size_t)T_SZ * B_SZ * INDIM * 2;
    unsigned short* hh0   = (unsigned short*)ws; ws += (size_t)B_SZ * 2 * HIDN * 2;
    unsigned short* hh1   = (unsigned short*)ws; ws += (size_t)B_SZ * 2 * HIDN * 2;
    float*          c1    = (float*)ws;          ws += (size_t)B_SZ * HIDN * 4;
    float*          c2    = (float*)ws;          ws += (size_t)B_SZ * HIDN * 4;
    unsigned short* xfut  = (unsigned short*)ws; ws += (size_t)B_SZ * INDIM * 2;

    // one-time (per-call) conversions — deterministic
    conv_strided<<<(4096 * 64 + 255) / 256, 256, 0, stream>>>(W_ih1, Wcat1, 64, 1088, 0, 4096 * 64);
    conv_strided<<<(4096 * 1024 + 255) / 256, 256, 0, stream>>>(W_hh1, Wcat1, 1024, 1088, 64, 4096 * 1024);
    conv_strided<<<(4096 * 1024 + 255) / 256, 256, 0, stream>>>(W_ih2, Wcat2, 1024, 2048, 0, 4096 * 1024);
    conv_strided<<<(4096 * 1024 + 255) / 256, 256, 0, stream>>>(W_hh2, Wcat2, 1024, 2048, 1024, 4096 * 1024);
    conv_strided<<<(64 * 1024 + 255) / 256, 256, 0, stream>>>(W_lin, Wlinb, 1024, 1024, 0, 64 * 1024);
    conv_strided<<<(64 * 64 + 255) / 256, 256, 0, stream>>>(W_o2i, Wo2ib, 64, 64, 0, 64 * 64);
    conv_x<<<(T_SZ * B_SZ * INDIM) / 256, 256, 0, stream>>>(input, xbf);

    hipMemsetAsync(hh0, 0, (size_t)B_SZ * 2 * HIDN * 2, stream);
    hipMemsetAsync(c1, 0, (size_t)B_SZ * HIDN * 4, stream);
    hipMemsetAsync(c2, 0, (size_t)B_SZ * HIDN * 4, stream);

    for (int t = 0; t < TF_SZ; ++t) {
        unsigned short* src = (t & 1) ? hh1 : hh0;   // holds h1(t-1) | h2(t-1)
        unsigned short* dst = (t & 1) ? hh0 : hh1;   // receives h1(t) | h2(t)
        const unsigned short* xsrc =
            (t < T_SZ) ? (xbf + (size_t)t * B_SZ * INDIM) : xfut;

        // layer 1: gates = x @ Wih1^T + h1_prev @ Whh1^T
        lstm_gemm_cell<<<dim3(4, 64), 256, 0, stream>>>(
            xsrc, INDIM, INDIM, src, HIDN, 2 * HIDN,
            Wcat1, b_ih1, b_hh1, c1, dst, 2 * HIDN);

        // layer 2: gates = h1_new @ Wih2^T + h2_prev @ Whh2^T
        lstm_gemm_cell<<<dim3(4, 64), 256, 0, stream>>>(
            dst, HIDN, 2 * HIDN, src + HIDN, HIDN, 2 * HIDN,
            Wcat2, b_ih2, b_hh2, c2, dst + HIDN, 2 * HIDN);

        const int fb = (t >= T_SZ - 1 && t < TF_SZ - 1) ? 1 : 0;
        out_kernel<<<64, 256, 0, stream>>>(
            dst + HIDN, Wlinb, b_lin, outp, t, Wo2ib, b_o2i, xfut, fb);
    }
}

// Round 2
// 11554.857 us; speedup vs baseline: 2.0182x; 2.0182x over previous
//
#include <hip/hip_runtime.h>
#include <hip/hip_bf16.h>

#define B_SZ   256
#define T_SZ   256
#define FUT    32
#define TF_SZ  (T_SZ + FUT)
#define HIDN   1024
#define INDIM  64
#define OUTDIM 64

typedef __attribute__((ext_vector_type(8))) short bf16x8;
typedef __attribute__((ext_vector_type(4))) float f32x4;

__device__ __forceinline__ float bf2f(unsigned short u) {
    union { unsigned int i; float f; } v; v.i = (unsigned int)u << 16; return v.f;
}
__device__ __forceinline__ unsigned short f2bf(float f) {
    union { float f; unsigned int i; } v; v.f = f;
    unsigned int r = v.i + 0x7FFFu + ((v.i >> 16) & 1u);
    return (unsigned short)(r >> 16);
}
__device__ __forceinline__ float sigm(float x) { return 1.0f / (1.0f + __expf(-x)); }

// ---------------------------------------------------------------------------
// Stage one K-chunk: A tile [64 rows][len cols] and W tile [64 n-rows][len]
// into LDS via global_load_lds(16B), with XOR-swizzled SOURCE addresses so the
// linear LDS dest holds data at swizzled positions (read side applies same XOR).
// W n-row r -> gate g = r>>4, hid q = r&15 -> global row g*HIDN + wrowbase + q.
// ---------------------------------------------------------------------------
__device__ __forceinline__ void stage_tile(
    char* dstA, char* dstW,
    const unsigned short* aptr, int astr, int akb, int Mbase,
    const unsigned short* W, int Ktot, int wrowbase, int kbase,
    int len, int tid)
{
    const int rsh  = (len == 128) ? 8 : 7;   // bytes-per-row shift
    const int rbm1 = len * 2 - 1;
    const int n = (64 * len * 2) >> 12;      // 16B instrs per thread per matrix
    for (int i = 0; i < n; ++i) {
        const int d  = (i * 256 + tid) * 16;
        const int r  = d >> rsh;
        const int cb = d & rbm1;
        const int scb = cb ^ ((r & 7) << 4);
        const char* srcA = (const char*)(aptr + (size_t)(Mbase + r) * astr + akb) + scb;
        __builtin_amdgcn_global_load_lds(
            (const __attribute__((address_space(1))) unsigned int*)srcA,
            (__attribute__((address_space(3))) unsigned int*)(dstA + d), 16, 0, 0);
    }
    for (int i = 0; i < n; ++i) {
        const int d  = (i * 256 + tid) * 16;
        const int r  = d >> rsh;
        const int cb = d & rbm1;
        const int scb = cb ^ ((r & 7) << 4);
        const int g = r >> 4, q = r & 15;
        const char* srcW = (const char*)(W + (size_t)(g * HIDN + wrowbase + q) * Ktot + kbase) + scb;
        __builtin_amdgcn_global_load_lds(
            (const __attribute__((address_space(1))) unsigned int*)srcW,
            (__attribute__((address_space(3))) unsigned int*)(dstW + d), 16, 0, 0);
    }
}

// ---------------------------------------------------------------------------
// GEMM (LDS double-buffered, swizzled) + fused LSTM cell + optional folded
// out(t-1) = h2(t-1) @ W_lin^T + b_lin (one out-column per block).
// Grid: 256 blocks x 256 threads. Block decode is XCD-stable so each XCD's
// W slice (~3.1 MB for both layers) stays resident in its private L2.
// Block tile: M=64 (xb), N=64 = 16 hidden x 4 gates (jb). Waves 2x2 over tile.
// ---------------------------------------------------------------------------
__global__ __launch_bounds__(256) void lstm_gemm_cell2(
    const unsigned short* __restrict__ a1, int K1, int s1,
    const unsigned short* __restrict__ a2, int s2,
    const unsigned short* __restrict__ W, int Ktot,
    const float* __restrict__ b_ih, const float* __restrict__ b_hh,
    float* __restrict__ cbuf,
    unsigned short* __restrict__ hdst, int hs,
    int do_out,
    const unsigned short* __restrict__ h2prev,   // row stride 2048
    const unsigned short* __restrict__ Wlin,     // [64][1024] bf16
    const float* __restrict__ blin,
    float* __restrict__ outp, int tprev)
{
    const int tid = threadIdx.x;
    const int id  = blockIdx.x;
    const int xcd = id & 7, sub = id >> 3;
    const int jb  = xcd * 8 + (sub & 7);   // N-tile 0..63 (XCD-stable)
    const int xb  = sub >> 3;              // M-tile 0..3
    const int Mbase = xb * 64;

    __shared__ char ldsA[32768];           // A dbuf; aliased: gates f32[64][64], red f32[256]
    __shared__ char ldsW[32768];           // W dbuf

    // ---- folded out(t-1): 64 rows x 1 col (col = jb), K = 1024 ----
    if (do_out) {
        const int row = tid & 63, kq = tid >> 6;
        const unsigned short* hrow = h2prev + (size_t)(Mbase + row) * 2048 + kq * 256;
        const unsigned short* wrow = Wlin + (size_t)jb * 1024 + kq * 256;
        float p = 0.f;
        for (int k = 0; k < 256; k += 8) {
            bf16x8 hv = *(const bf16x8*)(hrow + k);
            bf16x8 wv = *(const bf16x8*)(wrow + k);
#pragma unroll
            for (int u = 0; u < 8; ++u)
                p += bf2f((unsigned short)hv[u]) * bf2f((unsigned short)wv[u]);
        }
        float* red = (float*)ldsA;
        red[kq * 64 + row] = p;
        __syncthreads();
        if (tid < 64) {
            float s = red[tid] + red[64 + tid] + red[128 + tid] + red[192 + tid] + blin[jb];
            outp[((size_t)(Mbase + tid) * TF_SZ + tprev) * OUTDIM + jb] = s;
        }
        __syncthreads();
    }

    // ---- main GEMM over K chunks (first chunk len0, then 128s) ----
    const int lane = tid & 63;
    const int w    = tid >> 6;
    const int wm   = (w & 1) * 32, wn = (w >> 1) * 32;
    const int am   = lane & 15, ah = lane >> 4;

    f32x4 acc00 = {0.f,0.f,0.f,0.f}, acc01 = {0.f,0.f,0.f,0.f};
    f32x4 acc10 = {0.f,0.f,0.f,0.f}, acc11 = {0.f,0.f,0.f,0.f};

    const int wrowbase = jb * 16;
    const int len0 = (K1 == 64) ? 64 : 128;

    stage_tile(ldsA, ldsW, a1, s1, 0, Mbase, W, Ktot, wrowbase, 0, len0, tid);
    __syncthreads();

    int buf = 0, kb = 0, clen = len0;
    for (;;) {
        const int knext = kb + clen;
        const bool more = (knext < Ktot);
        if (more) {
            const unsigned short* ap; int astr, akb;
            if (knext < K1) { ap = a1; astr = s1; akb = knext; }
            else            { ap = a2; astr = s2; akb = knext - K1; }
            stage_tile(ldsA + (buf ^ 1) * 16384, ldsW + (buf ^ 1) * 16384,
                       ap, astr, akb, Mbase, W, Ktot, wrowbase, knext, 128, tid);
        }
        // compute current chunk from buf
        {
            const int rb = clen * 2;
            const char* abase = ldsA + buf * 16384;
            const char* wbase = ldsW + buf * 16384;
            for (int ks = 0; ks < clen; ks += 32) {
                const int cb0 = ks * 2 + ah * 16;
                int r0 = wm + am;
                bf16x8 av0 = *(const bf16x8*)(abase + r0 * rb + (cb0 ^ ((r0 & 7) << 4)));
                int r1 = wm + 16 + am;
                bf16x8 av1 = *(const bf16x8*)(abase + r1 * rb + (cb0 ^ ((r1 & 7) << 4)));
                int n0 = wn + am;
                bf16x8 wv0 = *(const bf16x8*)(wbase + n0 * rb + (cb0 ^ ((n0 & 7) << 4)));
                int n1 = wn + 16 + am;
                bf16x8 wv1 = *(const bf16x8*)(wbase + n1 * rb + (cb0 ^ ((n1 & 7) << 4)));
                acc00 = __builtin_amdgcn_mfma_f32_16x16x32_bf16(av0, wv0, acc00, 0, 0, 0);
                acc01 = __builtin_amdgcn_mfma_f32_16x16x32_bf16(av0, wv1, acc01, 0, 0, 0);
                acc10 = __builtin_amdgcn_mfma_f32_16x16x32_bf16(av1, wv0, acc10, 0, 0, 0);
                acc11 = __builtin_amdgcn_mfma_f32_16x16x32_bf16(av1, wv1, acc11, 0, 0, 0);
            }
        }
        __syncthreads();
        if (!more) break;
        buf ^= 1; kb = knext; clen = 128;
    }

    // ---- gates to LDS (alias ldsA; all tile reads are done) ----
    float* gates = (float*)ldsA;   // [64 rows][64 n-cols] f32
#pragma unroll
    for (int rg = 0; rg < 4; ++rg) {
        gates[(wm +      ah * 4 + rg) * 64 + (wn +      am)] = acc00[rg];
        gates[(wm +      ah * 4 + rg) * 64 + (wn + 16 + am)] = acc01[rg];
        gates[(wm + 16 + ah * 4 + rg) * 64 + (wn +      am)] = acc10[rg];
        gates[(wm + 16 + ah * 4 + rg) * 64 + (wn + 16 + am)] = acc11[rg];
    }
    __syncthreads();

    // ---- cell update epilogue: 4 cells per thread ----
    const int hq = tid & 15;       // hidden within tile
    const int rq = tid >> 4;       // row group
    const int j  = jb * 16 + hq;
    const float bi  = b_ih[j]            + b_hh[j];
    const float bff = b_ih[HIDN + j]     + b_hh[HIDN + j];
    const float bg  = b_ih[2 * HIDN + j] + b_hh[2 * HIDN + j];
    const float bo  = b_ih[3 * HIDN + j] + b_hh[3 * HIDN + j];
#pragma unroll
    for (int ii = 0; ii < 4; ++ii) {
        const int row = rq + 16 * ii;
        const float ig = sigm(gates[row * 64 +      hq] + bi);
        const float fg = sigm(gates[row * 64 + 16 + hq] + bff);
        const float gg = tanhf(gates[row * 64 + 32 + hq] + bg);
        const float og = sigm(gates[row * 64 + 48 + hq] + bo);
        const size_t ci = (size_t)(Mbase + row) * HIDN + j;
        const float cn = fg * cbuf[ci] + ig * gg;
        cbuf[ci] = cn;
        hdst[(size_t)(Mbase + row) * hs + j] = f2bf(og * tanhf(cn));
    }
}

// ---------------------------------------------------------------------------
// out + optional feedback (used only for t = 255..287)
// ---------------------------------------------------------------------------
__global__ __launch_bounds__(256) void out_kernel(
    const unsigned short* __restrict__ h2,   // row stride 2048
    const unsigned short* __restrict__ Wlin,
    const float* __restrict__ blin,
    float* __restrict__ outp, int t,
    const unsigned short* __restrict__ Wo2i,
    const float* __restrict__ bo2i,
    unsigned short* __restrict__ xfut, int do_fb)
{
    __shared__ unsigned short h2s[4][HIDN];
    __shared__ float outs[4][OUTDIM];
    const int tid = threadIdx.x;
    const int rl  = tid >> 6;
    const int col = tid & 63;
    const int rowbase = blockIdx.x * 4;

    for (int i = tid; i < 4 * HIDN / 8; i += 256) {
        const int rr = i >> 7, kk = (i & 127) * 8;
        *(bf16x8*)&h2s[rr][kk] =
            *(const bf16x8*)&h2[(size_t)(rowbase + rr) * 2048 + kk];
    }
    __syncthreads();

    float acc = blin[col];
    const unsigned short* wrow = Wlin + (size_t)col * HIDN;
    for (int k = 0; k < HIDN; k += 8) {
        bf16x8 hv = *(const bf16x8*)&h2s[rl][k];
        bf16x8 wv = *(const bf16x8*)&wrow[k];
#pragma unroll
        for (int u = 0; u < 8; ++u)
            acc += bf2f((unsigned short)hv[u]) * bf2f((unsigned short)wv[u]);
    }
    const int row = rowbase + rl;
    outp[((size_t)row * TF_SZ + t) * OUTDIM + col] = acc;

    if (do_fb) {
        outs[rl][col] = acc;
        __syncthreads();
        float x = bo2i[col];
        const unsigned short* w2 = Wo2i + (size_t)col * OUTDIM;
#pragma unroll 8
        for (int jj = 0; jj < OUTDIM; ++jj)
            x += outs[rl][jj] * bf2f(w2[jj]);
        xfut[(size_t)row * INDIM + col] = f2bf(x);
    }
}

__global__ void conv_strided(const float* __restrict__ src,
                             unsigned short* __restrict__ dst,
                             int cols, int dstride, int doff, int total)
{
    const int idx = blockIdx.x * 256 + threadIdx.x;
    if (idx >= total) return;
    const int r = idx / cols, c = idx - r * cols;
    dst[(size_t)r * dstride + doff + c] = f2bf(src[idx]);
}

__global__ void conv_x(const float* __restrict__ src,
                       unsigned short* __restrict__ dst)
{
    const int idx = blockIdx.x * 256 + threadIdx.x;
    const int f = idx & 63, t = (idx >> 6) & 255, b = idx >> 14;
    dst[((size_t)t * B_SZ + b) * INDIM + f] = f2bf(src[idx]);
}

extern "C" void kernel_launch(void* const* d_in, const int* in_sizes, int n_in,
                              void* d_out, int out_size, void* d_ws, size_t ws_size,
                              hipStream_t stream)
{
    const float* input = (const float*)d_in[0];
    const float* W_ih1 = (const float*)d_in[1];
    const float* W_hh1 = (const float*)d_in[2];
    const float* b_ih1 = (const float*)d_in[3];
    const float* b_hh1 = (const float*)d_in[4];
    const float* W_ih2 = (const float*)d_in[5];
    const float* W_hh2 = (const float*)d_in[6];
    const float* b_ih2 = (const float*)d_in[7];
    const float* b_hh2 = (const float*)d_in[8];
    const float* W_lin = (const float*)d_in[9];
    const float* b_lin = (const float*)d_in[10];
    const float* W_o2i = (const float*)d_in[11];
    const float* b_o2i = (const float*)d_in[12];
    float* outp = (float*)d_out;

    char* ws = (char*)d_ws;
    unsigned short* Wcat1 = (unsigned short*)ws; ws += (size_t)4096 * 1088 * 2;
    unsigned short* Wcat2 = (unsigned short*)ws; ws += (size_t)4096 * 2048 * 2;
    unsigned short* Wlinb = (unsigned short*)ws; ws += (size_t)64 * 1024 * 2;
    unsigned short* Wo2ib = (unsigned short*)ws; ws += (size_t)64 * 64 * 2;
    unsigned short* xbf   = (unsigned short*)ws; ws += (size_t)T_SZ * B_SZ * INDIM * 2;
    unsigned short* hh0   = (unsigned short*)ws; ws += (size_t)B_SZ * 2 * HIDN * 2;
    unsigned short* hh1   = (unsigned short*)ws; ws += (size_t)B_SZ * 2 * HIDN * 2;
    float*          c1    = (float*)ws;          ws += (size_t)B_SZ * HIDN * 4;
    float*          c2    = (float*)ws;          ws += (size_t)B_SZ * HIDN * 4;
    unsigned short* xfut  = (unsigned short*)ws; ws += (size_t)B_SZ * INDIM * 2;

    conv_strided<<<(4096 * 64 + 255) / 256, 256, 0, stream>>>(W_ih1, Wcat1, 64, 1088, 0, 4096 * 64);
    conv_strided<<<(4096 * 1024 + 255) / 256, 256, 0, stream>>>(W_hh1, Wcat1, 1024, 1088, 64, 4096 * 1024);
    conv_strided<<<(4096 * 1024 + 255) / 256, 256, 0, stream>>>(W_ih2, Wcat2, 1024, 2048, 0, 4096 * 1024);
    conv_strided<<<(4096 * 1024 + 255) / 256, 256, 0, stream>>>(W_hh2, Wcat2, 1024, 2048, 1024, 4096 * 1024);
    conv_strided<<<(64 * 1024 + 255) / 256, 256, 0, stream>>>(W_lin, Wlinb, 1024, 1024, 0, 64 * 1024);
    conv_strided<<<(64 * 64 + 255) / 256, 256, 0, stream>>>(W_o2i, Wo2ib, 64, 64, 0, 64 * 64);
    conv_x<<<(T_SZ * B_SZ * INDIM) / 256, 256, 0, stream>>>(input, xbf);

    hipMemsetAsync(hh0, 0, (size_t)B_SZ * 2 * HIDN * 2, stream);
    hipMemsetAsync(c1, 0, (size_t)B_SZ * HIDN * 4, stream);
    hipMemsetAsync(c2, 0, (size_t)B_SZ * HIDN * 4, stream);

    for (int t = 0; t < TF_SZ; ++t) {
        unsigned short* src = (t & 1) ? hh1 : hh0;   // h1(t-1) | h2(t-1)
        unsigned short* dst = (t & 1) ? hh0 : hh1;   // h1(t)   | h2(t)
        const unsigned short* xsrc =
            (t < T_SZ) ? (xbf + (size_t)t * B_SZ * INDIM) : xfut;
        const int do_out = (t >= 1 && t <= 255) ? 1 : 0;

        // layer 1 (+ folded out(t-1))
        lstm_gemm_cell2<<<256, 256, 0, stream>>>(
            xsrc, 64, 64, src, 2 * HIDN, Wcat1, 1088,
            b_ih1, b_hh1, c1, dst, 2 * HIDN,
            do_out, src + HIDN, Wlinb, b_lin, outp, (t > 0) ? (t - 1) : 0);

        // layer 2
        lstm_gemm_cell2<<<256, 256, 0, stream>>>(
            dst, 1024, 2 * HIDN, src + HIDN, 2 * HIDN, Wcat2, 2048,
            b_ih2, b_hh2, c2, dst + HIDN, 2 * HIDN,
            0, nullptr, nullptr, nullptr, nullptr, 0);

        // out + feedback only for the tail (t = 255..287)
        if (t >= T_SZ - 1) {
            const int fb = (t < TF_SZ - 1) ? 1 : 0;
            out_kernel<<<64, 256, 0, stream>>>(
                dst + HIDN, Wlinb, b_lin, outp, t, Wo2ib, b_o2i, xfut, fb);
        }
    }
}